// Round 9
// baseline (14957.634 us; speedup 1.0000x reference)
//
#include <hip/hip_runtime.h>
#include <cstdint>

typedef unsigned short u16;
typedef unsigned int   u32;

#define NL 3
#define NC 4
#define NB 16
#define NT 4096
#define MR (NB*NT)   // 65536 rows

// ---------------- weight prep: Wih scaled by exp(-log_s), fp32 ----------------
__global__ void k_scale_wih_f32(const float* __restrict__ wih, const float* __restrict__ ls,
                                float* __restrict__ dst, int n){
    int i = blockIdx.x * 256 + threadIdx.x;
    if (i >= n) return;
    int lc = i / (192 * 256);          // 0..11 -> (layer*4 + channel)
    float sc = expf(-ls[lc]);
    dst[i] = wih[i] * sc;
}

// ---------------- GEMM fp32: C = act(A @ W^T + bias) -------------------------
// UNCHANGED from passing rounds 6/7/8.
__global__ __launch_bounds__(256) void k_gemm_f32(
    const float* __restrict__ A, const float* __restrict__ W,
    const float* __restrict__ bias, float* __restrict__ Cdst,
    int M, int N, int K, int act)
{
    __shared__ float sA[64][33];
    __shared__ float sB[64][33];

    const int tid = threadIdx.x;
    const int bm = blockIdx.x, bn = blockIdx.y;
    const int ty = tid >> 4;
    const int tx = tid & 15;

    float acc[4][4] = {};

    const int lr = tid >> 2;            // staging row 0..63
    const int lc = (tid & 3) * 8;       // staging col 0,8,16,24

    for (int kk = 0; kk < K; kk += 32) {
        const float* ap = A + (size_t)(bm * 64 + lr) * K + kk + lc;
        const float* bp = W + (size_t)(bn * 64 + lr) * K + kk + lc;
        __syncthreads();
        float4 a0 = *(const float4*)(ap);
        float4 a1 = *(const float4*)(ap + 4);
        float4 b0 = *(const float4*)(bp);
        float4 b1 = *(const float4*)(bp + 4);
        *(float4*)&sA[lr][lc]     = a0;
        *(float4*)&sA[lr][lc + 4] = a1;
        *(float4*)&sB[lr][lc]     = b0;
        *(float4*)&sB[lr][lc + 4] = b1;
        __syncthreads();

        #pragma unroll
        for (int k = 0; k < 32; k++) {
            float av[4], bv[4];
            #pragma unroll
            for (int i = 0; i < 4; i++) av[i] = sA[ty * 4 + i][k];
            #pragma unroll
            for (int j = 0; j < 4; j++) bv[j] = sB[tx * 4 + j][k];
            #pragma unroll
            for (int i = 0; i < 4; i++)
                #pragma unroll
                for (int j = 0; j < 4; j++)
                    acc[i][j] = fmaf(av[i], bv[j], acc[i][j]);
        }
    }

    #pragma unroll
    for (int i = 0; i < 4; i++) {
        int row = bm * 64 + ty * 4 + i;
        #pragma unroll
        for (int j = 0; j < 4; j++) {
            int col = bn * 64 + tx * 4 + j;
            float v = acc[i][j] + bias[col];
            if (act) v = tanhf(v);
            Cdst[(size_t)row * N + col] = v;
        }
    }
}

// ---------------- GRU scan: 4 waves, k-split, 1 barrier/step -----------------
// Wave w owns k-range [16w,16w+16): 48 weight floats/lane (VGPR-resident).
// Partials exchanged via parity-double-buffered LDS; final update replicated
// in all 4 waves (bit-identical); wave 0 stores.
__device__ __forceinline__ float rl(float v, int k){
    return __uint_as_float((u32)__builtin_amdgcn_readlane((int)__float_as_uint(v), k));
}
__device__ __forceinline__ float fsig(float x){
    return 1.0f / (1.0f + __expf(-x));
}
__device__ __forceinline__ float ftanh(float x){
    float e = __expf(-2.0f * fabsf(x));
    float t = (1.0f - e) / (1.0f + e);
    return copysignf(t, x);
}

__global__ __launch_bounds__(256, 1) void k_scan4(
    const float* __restrict__ ig,   // (bch*NT,768): row lb*NT+t, col c*192+g*64+j (bias added)
    const float* __restrict__ Whh,  // layer base: (C,192,64)
    const float* __restrict__ bnp,  // (C,64)
    const float* __restrict__ lsp,  // (C)
    const float* __restrict__ h0p,  // (C,B,64) layer base
    float* __restrict__ ynew,       // layer base: (C,B,T,64) f32 (d_out)
    float* __restrict__ xc,         // (MR,256) f32: concat-channel buffer
    int b0)
{
    const int c  = blockIdx.x;
    const int lb = blockIdx.y;
    const int b  = b0 + lb;
    const int tid = threadIdx.x;
    const int w  = tid >> 6;        // wave 0..3
    const int j  = tid & 63;
    const int k0 = w * 16;          // this wave's k-range start

    // 48 weight floats per lane: rows j / 64+j / 128+j, cols [k0,k0+16)
    float wr[16], wz[16], wn[16];
    {
        const float* pr = Whh + (size_t)(c * 192 +       j) * 64 + k0;
        const float* pz = Whh + (size_t)(c * 192 +  64 + j) * 64 + k0;
        const float* pn = Whh + (size_t)(c * 192 + 128 + j) * 64 + k0;
        #pragma unroll
        for (int k = 0; k < 16; k += 4) {
            float4 a = *(const float4*)(pr + k);
            float4 d = *(const float4*)(pz + k);
            float4 e = *(const float4*)(pn + k);
            wr[k]=a.x; wr[k+1]=a.y; wr[k+2]=a.z; wr[k+3]=a.w;
            wz[k]=d.x; wz[k+1]=d.y; wz[k+2]=d.z; wz[k+3]=d.w;
            wn[k]=e.x; wn[k+1]=e.y; wn[k+2]=e.z; wn[k+3]=e.w;
        }
    }

    float hj = h0p[(c * NB + b) * 64 + j];
    const float rs  = expf(-lsp[c]);     // 1/s
    const float bnj = bnp[c * 64 + j];

    // [parity][gate][wave][j]: dword addr = ((p*3+g)*4+w)*64+j -> bank j%32,
    // 2 lanes/bank (free, m136)
    __shared__ float part[2][3][4][64];

    const float* igp = ig + (size_t)(lb * NT) * 768 + c * 192;
    float* yp = ynew + ((size_t)(c * NB + b) * NT) * 64 + j;
    float* xp = xc + (size_t)(b * NT) * 256 + c * 64 + j;

    // distance-2 prefetch of the 3 ig streams (all waves: needed for replicated update)
    float pr0 = igp[j],       pz0 = igp[64 + j],       pn0 = igp[128 + j];
    float pr1 = igp[768 + j], pz1 = igp[768 + 64 + j], pn1 = igp[768 + 128 + j];

    for (int t = 0; t < NT; t++) {
        float igr = pr0, igz = pz0, ign = pn0;
        pr0 = pr1; pz0 = pz1; pn0 = pn1;
        if (t + 2 < NT) {
            const float* nx = igp + (size_t)(t + 2) * 768;
            pr1 = nx[j]; pz1 = nx[64 + j]; pn1 = nx[128 + j];
        }

        // partial dots over this wave's 16 k, 4-way chains
        float ar0=0.f, ar1=0.f, ar2=0.f, ar3=0.f;
        float az0=0.f, az1=0.f, az2=0.f, az3=0.f;
        float an0=0.f, an1=0.f, an2=0.f, an3=0.f;
        #pragma unroll
        for (int k = 0; k < 16; k += 4) {
            float h0v = rl(hj, k0 + k);
            ar0 = fmaf(h0v, wr[k],   ar0);
            az0 = fmaf(h0v, wz[k],   az0);
            an0 = fmaf(h0v, wn[k],   an0);
            float h1v = rl(hj, k0 + k + 1);
            ar1 = fmaf(h1v, wr[k+1], ar1);
            az1 = fmaf(h1v, wz[k+1], az1);
            an1 = fmaf(h1v, wn[k+1], an1);
            float h2v = rl(hj, k0 + k + 2);
            ar2 = fmaf(h2v, wr[k+2], ar2);
            az2 = fmaf(h2v, wz[k+2], az2);
            an2 = fmaf(h2v, wn[k+2], an2);
            float h3v = rl(hj, k0 + k + 3);
            ar3 = fmaf(h3v, wr[k+3], ar3);
            az3 = fmaf(h3v, wz[k+3], az3);
            an3 = fmaf(h3v, wn[k+3], an3);
        }
        const int p = t & 1;
        part[p][0][w][j] = (ar0 + ar1) + (ar2 + ar3);
        part[p][1][w][j] = (az0 + az1) + (az2 + az3);
        part[p][2][w][j] = (an0 + an1) + (an2 + an3);
        __syncthreads();

        float accr = (part[p][0][0][j] + part[p][0][1][j])
                   + (part[p][0][2][j] + part[p][0][3][j]);
        float accz = (part[p][1][0][j] + part[p][1][1][j])
                   + (part[p][1][2][j] + part[p][1][3][j]);
        float accn = (part[p][2][0][j] + part[p][2][1][j])
                   + (part[p][2][2][j] + part[p][2][3][j]);

        // replicated in all 4 waves -> identical bits -> consistent hj
        float r  = fsig(igr + accr);
        float z  = fsig(igz + accz);
        float n  = ftanh(ign + r * (accn + bnj));
        float hn = n + z * (hj - n);
        float y  = hj + (hn - hj) * rs;     // (hn-h)/s + h

        if (w == 0) {
            yp[(size_t)t * 64]  = y;
            xp[(size_t)t * 256] = y;
        }
        hj = y;
    }
}

// ---------------- launch ----------------
extern "C" void kernel_launch(void* const* d_in, const int* in_sizes, int n_in,
                              void* d_out, int out_size, void* d_ws, size_t ws_size,
                              hipStream_t stream)
{
    const float* in_inputs = (const float*)d_in[0];
    const float* h0    = (const float*)d_in[1];
    const float* encW1 = (const float*)d_in[3];
    const float* encB1 = (const float*)d_in[4];
    const float* encW2 = (const float*)d_in[5];
    const float* encB2 = (const float*)d_in[6];
    const float* gWih  = (const float*)d_in[7];
    const float* gWhh  = (const float*)d_in[8];
    const float* gB    = (const float*)d_in[9];
    const float* gBn   = (const float*)d_in[10];
    const float* logS  = (const float*)d_in[11];
    const float* mW1   = (const float*)d_in[12];
    const float* mB1   = (const float*)d_in[13];
    const float* mW2   = (const float*)d_in[14];
    const float* mB2   = (const float*)d_in[15];

    float* out_f  = (float*)d_out;                    // (B,T,256) f32
    float* ynew_f = out_f + (size_t)MR * 256;         // (L,C,B,T,64) f32

    // ---- adaptive chunking: maximize batches-per-chunk within ws_size ----
    const size_t xa_b  = (size_t)MR * 256 * 4;                 // 67.11 MB
    const size_t xc_b  = xa_b;                                 // 67.11 MB
    const size_t wih_b = (size_t)NL * NC * 192 * 256 * 4;      // 2.36 MB
    int bch = 16;
    for (;;) {
        size_t igb = (size_t)bch * NT * 768 * 4;
        size_t r0  = igb > xa_b ? igb : xa_b;   // XB aliases region 0
        if (r0 + xa_b + xc_b + wih_b + 4096 <= ws_size || bch == 1) break;
        bch >>= 1;
    }
    const int nch = NB / bch;
    const int mch = bch * NT;

    char* ws = (char*)d_ws;
    size_t off = 0;
    auto alloc = [&](size_t bytes) -> void* {
        void* p = ws + off;
        off = (off + bytes + 255) & ~(size_t)255;
        return p;
    };
    size_t igb = (size_t)bch * NT * 768 * 4;
    float* IG  = (float*)alloc(igb > xa_b ? igb : xa_b);  // region 0
    float* XB  = IG;                                       // alias: lifetimes disjoint
    float* XA  = (float*)alloc(xa_b);
    float* XC  = (float*)alloc(xc_b);
    float* WIHs= (float*)alloc(wih_b);

    int nWih = NL * NC * 192 * 256;
    k_scale_wih_f32<<<(nWih + 255) / 256, 256, 0, stream>>>(gWih, logS, WIHs, nWih);

    dim3 blk(256);
    // encoder: XB = tanh(inputs @ W1^T + b1); XA = XB @ W2^T + b2
    k_gemm_f32<<<dim3(MR / 64, 256 / 64), blk, 0, stream>>>(in_inputs, encW1, encB1, XB, MR, 256, 128, 1);
    k_gemm_f32<<<dim3(MR / 64, 256 / 64), blk, 0, stream>>>(XB, encW2, encB2, XA, MR, 256, 256, 0);

    for (int l = 0; l < NL; l++) {
        for (int ch = 0; ch < nch; ch++) {
            k_gemm_f32<<<dim3(mch / 64, 768 / 64), blk, 0, stream>>>(
                XA + (size_t)ch * mch * 256, WIHs + (size_t)l * NC * 192 * 256,
                gB + l * 768, IG, mch, 768, 256, 0);
            k_scan4<<<dim3(NC, bch), dim3(256), 0, stream>>>(
                IG, gWhh + (size_t)l * NC * 192 * 64, gBn + l * NC * 64, logS + l * NC,
                h0 + (size_t)l * NC * NB * 64,
                ynew_f + (size_t)l * NC * NB * NT * 64, XC, ch * bch);
        }
        // inter-layer MLP (XB aliases IG; IG dead after scans consumed it)
        k_gemm_f32<<<dim3(MR / 64, 256 / 64), blk, 0, stream>>>(
            XC, mW1 + (size_t)l * 256 * 256, mB1 + l * 256, XB, MR, 256, 256, 1);
        k_gemm_f32<<<dim3(MR / 64, 256 / 64), blk, 0, stream>>>(
            XB, mW2 + (size_t)l * 256 * 256, mB2 + l * 256, XA, MR, 256, 256, 0);
    }
    // faithful to source: mlps[-1] applied a second time -> out (f32)
    k_gemm_f32<<<dim3(MR / 64, 256 / 64), blk, 0, stream>>>(
        XA, mW1 + (size_t)2 * 256 * 256, mB1 + 2 * 256, XB, MR, 256, 256, 1);
    k_gemm_f32<<<dim3(MR / 64, 256 / 64), blk, 0, stream>>>(
        XB, mW2 + (size_t)2 * 256 * 256, mB2 + 2 * 256, out_f, MR, 256, 256, 0);
}

// Round 10
// 10411.304 us; speedup vs baseline: 1.4367x; 1.4367x over previous
//
#include <hip/hip_runtime.h>
#include <cstdint>

typedef unsigned short u16;
typedef unsigned int   u32;
typedef __attribute__((ext_vector_type(2))) float f32x2;

#define NL 3
#define NC 4
#define NB 16
#define NT 4096
#define MR (NB*NT)   // 65536 rows

// ---------------- weight prep: Wih scaled by exp(-log_s), fp32 ----------------
__global__ void k_scale_wih_f32(const float* __restrict__ wih, const float* __restrict__ ls,
                                float* __restrict__ dst, int n){
    int i = blockIdx.x * 256 + threadIdx.x;
    if (i >= n) return;
    int lc = i / (192 * 256);          // 0..11 -> (layer*4 + channel)
    float sc = expf(-ls[lc]);
    dst[i] = wih[i] * sc;
}

// ---------------- GEMM fp32: C = act(A @ W^T + bias) -------------------------
// UNCHANGED from passing rounds 6-9.
__global__ __launch_bounds__(256) void k_gemm_f32(
    const float* __restrict__ A, const float* __restrict__ W,
    const float* __restrict__ bias, float* __restrict__ Cdst,
    int M, int N, int K, int act)
{
    __shared__ float sA[64][33];
    __shared__ float sB[64][33];

    const int tid = threadIdx.x;
    const int bm = blockIdx.x, bn = blockIdx.y;
    const int ty = tid >> 4;
    const int tx = tid & 15;

    float acc[4][4] = {};

    const int lr = tid >> 2;            // staging row 0..63
    const int lc = (tid & 3) * 8;       // staging col 0,8,16,24

    for (int kk = 0; kk < K; kk += 32) {
        const float* ap = A + (size_t)(bm * 64 + lr) * K + kk + lc;
        const float* bp = W + (size_t)(bn * 64 + lr) * K + kk + lc;
        __syncthreads();
        float4 a0 = *(const float4*)(ap);
        float4 a1 = *(const float4*)(ap + 4);
        float4 b0 = *(const float4*)(bp);
        float4 b1 = *(const float4*)(bp + 4);
        *(float4*)&sA[lr][lc]     = a0;
        *(float4*)&sA[lr][lc + 4] = a1;
        *(float4*)&sB[lr][lc]     = b0;
        *(float4*)&sB[lr][lc + 4] = b1;
        __syncthreads();

        #pragma unroll
        for (int k = 0; k < 32; k++) {
            float av[4], bv[4];
            #pragma unroll
            for (int i = 0; i < 4; i++) av[i] = sA[ty * 4 + i][k];
            #pragma unroll
            for (int j = 0; j < 4; j++) bv[j] = sB[tx * 4 + j][k];
            #pragma unroll
            for (int i = 0; i < 4; i++)
                #pragma unroll
                for (int j = 0; j < 4; j++)
                    acc[i][j] = fmaf(av[i], bv[j], acc[i][j]);
        }
    }

    #pragma unroll
    for (int i = 0; i < 4; i++) {
        int row = bm * 64 + ty * 4 + i;
        #pragma unroll
        for (int j = 0; j < 4; j++) {
            int col = bn * 64 + tx * 4 + j;
            float v = acc[i][j] + bias[col];
            if (act) v = tanhf(v);
            Cdst[(size_t)row * N + col] = v;
        }
    }
}

// ---------------- GRU scan: single wave, v_pk_fma_f32, LDS h-broadcast -------
// Lane j owns hidden unit j. Weights as 96 f32x2 in arch VGPRs (asm "v"
// operands force VGPR residency). h mirrored in LDS; read as 32 uniform-addr
// ds_read_b64 pair-broadcasts (no readlane, no SGPR hazards, LDS || VALU).
__device__ __forceinline__ float fsig(float x){
    return 1.0f / (1.0f + __expf(-x));
}
__device__ __forceinline__ float ftanh(float x){
    float e = __expf(-2.0f * fabsf(x));
    float t = (1.0f - e) / (1.0f + e);
    return copysignf(t, x);
}
__device__ __forceinline__ void pkfma(f32x2& acc, f32x2 a, f32x2 b){
    asm("v_pk_fma_f32 %0, %1, %2, %0" : "+v"(acc) : "v"(a), "v"(b));
}

__global__ __launch_bounds__(64, 1) void k_scanp(
    const float* __restrict__ ig,   // (bch*NT,768): row lb*NT+t, col c*192+g*64+j (bias added)
    const float* __restrict__ Whh,  // layer base: (C,192,64)
    const float* __restrict__ bnp,  // (C,64)
    const float* __restrict__ lsp,  // (C)
    const float* __restrict__ h0p,  // (C,B,64) layer base
    float* __restrict__ ynew,       // layer base: (C,B,T,64) f32 (d_out)
    float* __restrict__ xc,         // (MR,256) f32: concat-channel buffer
    int b0)
{
    const int c  = blockIdx.x;
    const int lb = blockIdx.y;
    const int b  = b0 + lb;
    const int j  = threadIdx.x;     // 0..63

    // 96 weight pairs per lane (192 f32): rows j / 64+j / 128+j of Whh
    f32x2 wr[32], wz[32], wn[32];
    {
        const float* pr = Whh + (size_t)(c * 192 +       j) * 64;
        const float* pz = Whh + (size_t)(c * 192 +  64 + j) * 64;
        const float* pn = Whh + (size_t)(c * 192 + 128 + j) * 64;
        #pragma unroll
        for (int i = 0; i < 32; i++) {
            wr[i] = *(const f32x2*)(pr + 2 * i);
            wz[i] = *(const f32x2*)(pz + 2 * i);
            wn[i] = *(const f32x2*)(pn + 2 * i);
        }
    }

    __shared__ float hsh[64];
    float hj = h0p[(c * NB + b) * 64 + j];
    hsh[j] = hj;
    __syncthreads();

    const float rs  = expf(-lsp[c]);     // 1/s
    const float bnj = bnp[c * 64 + j];

    const float* igp = ig + (size_t)(lb * NT) * 768 + c * 192;
    float* yp = ynew + ((size_t)(c * NB + b) * NT) * 64 + j;
    float* xp = xc + (size_t)(b * NT) * 256 + c * 64 + j;

    // distance-2 prefetch of the 3 ig streams
    float pr0 = igp[j],       pz0 = igp[64 + j],       pn0 = igp[128 + j];
    float pr1 = igp[768 + j], pz1 = igp[768 + 64 + j], pn1 = igp[768 + 128 + j];

    const f32x2* hp = (const f32x2*)hsh;

    for (int t = 0; t < NT; t++) {
        float igr = pr0, igz = pz0, ign = pn0;
        pr0 = pr1; pz0 = pz1; pn0 = pn1;
        if (t + 2 < NT) {
            const float* nx = igp + (size_t)(t + 2) * 768;
            pr1 = nx[j]; pz1 = nx[64 + j]; pn1 = nx[128 + j];
        }

        // 6 packed accumulator chains (2 per gate), 32 pair-broadcast reads
        f32x2 ar0 = {0.f, 0.f}, ar1 = {0.f, 0.f};
        f32x2 az0 = {0.f, 0.f}, az1 = {0.f, 0.f};
        f32x2 an0 = {0.f, 0.f}, an1 = {0.f, 0.f};
        #pragma unroll
        for (int i = 0; i < 32; i += 2) {
            f32x2 h0 = hp[i];
            pkfma(ar0, h0, wr[i]);
            pkfma(az0, h0, wz[i]);
            pkfma(an0, h0, wn[i]);
            f32x2 h1 = hp[i + 1];
            pkfma(ar1, h1, wr[i + 1]);
            pkfma(az1, h1, wz[i + 1]);
            pkfma(an1, h1, wn[i + 1]);
        }
        float accr = (ar0.x + ar0.y) + (ar1.x + ar1.y);
        float accz = (az0.x + az0.y) + (az1.x + az1.y);
        float accn = (an0.x + an0.y) + (an1.x + an1.y);

        float r  = fsig(igr + accr);
        float z  = fsig(igz + accz);
        float n  = ftanh(ign + r * (accn + bnj));
        float hn = n + z * (hj - n);
        float y  = hj + (hn - hj) * rs;     // (hn-h)/s + h

        hsh[j] = y;                          // publish for next step
        yp[(size_t)t * 64]  = y;
        xp[(size_t)t * 256] = y;
        hj = y;
        __syncthreads();                     // single-wave: waitcnt + cheap barrier
    }
}

// ---------------- launch ----------------
extern "C" void kernel_launch(void* const* d_in, const int* in_sizes, int n_in,
                              void* d_out, int out_size, void* d_ws, size_t ws_size,
                              hipStream_t stream)
{
    const float* in_inputs = (const float*)d_in[0];
    const float* h0    = (const float*)d_in[1];
    const float* encW1 = (const float*)d_in[3];
    const float* encB1 = (const float*)d_in[4];
    const float* encW2 = (const float*)d_in[5];
    const float* encB2 = (const float*)d_in[6];
    const float* gWih  = (const float*)d_in[7];
    const float* gWhh  = (const float*)d_in[8];
    const float* gB    = (const float*)d_in[9];
    const float* gBn   = (const float*)d_in[10];
    const float* logS  = (const float*)d_in[11];
    const float* mW1   = (const float*)d_in[12];
    const float* mB1   = (const float*)d_in[13];
    const float* mW2   = (const float*)d_in[14];
    const float* mB2   = (const float*)d_in[15];

    float* out_f  = (float*)d_out;                    // (B,T,256) f32
    float* ynew_f = out_f + (size_t)MR * 256;         // (L,C,B,T,64) f32

    // ---- adaptive chunking: maximize batches-per-chunk within ws_size ----
    const size_t xa_b  = (size_t)MR * 256 * 4;                 // 67.11 MB
    const size_t xc_b  = xa_b;                                 // 67.11 MB
    const size_t wih_b = (size_t)NL * NC * 192 * 256 * 4;      // 2.36 MB
    int bch = 16;
    for (;;) {
        size_t igb = (size_t)bch * NT * 768 * 4;
        size_t r0  = igb > xa_b ? igb : xa_b;   // XB aliases region 0
        if (r0 + xa_b + xc_b + wih_b + 4096 <= ws_size || bch == 1) break;
        bch >>= 1;
    }
    const int nch = NB / bch;
    const int mch = bch * NT;

    char* ws = (char*)d_ws;
    size_t off = 0;
    auto alloc = [&](size_t bytes) -> void* {
        void* p = ws + off;
        off = (off + bytes + 255) & ~(size_t)255;
        return p;
    };
    size_t igb = (size_t)bch * NT * 768 * 4;
    float* IG  = (float*)alloc(igb > xa_b ? igb : xa_b);  // region 0
    float* XB  = IG;                                       // alias: lifetimes disjoint
    float* XA  = (float*)alloc(xa_b);
    float* XC  = (float*)alloc(xc_b);
    float* WIHs= (float*)alloc(wih_b);

    int nWih = NL * NC * 192 * 256;
    k_scale_wih_f32<<<(nWih + 255) / 256, 256, 0, stream>>>(gWih, logS, WIHs, nWih);

    dim3 blk(256);
    // encoder: XB = tanh(inputs @ W1^T + b1); XA = XB @ W2^T + b2
    k_gemm_f32<<<dim3(MR / 64, 256 / 64), blk, 0, stream>>>(in_inputs, encW1, encB1, XB, MR, 256, 128, 1);
    k_gemm_f32<<<dim3(MR / 64, 256 / 64), blk, 0, stream>>>(XB, encW2, encB2, XA, MR, 256, 256, 0);

    for (int l = 0; l < NL; l++) {
        for (int ch = 0; ch < nch; ch++) {
            k_gemm_f32<<<dim3(mch / 64, 768 / 64), blk, 0, stream>>>(
                XA + (size_t)ch * mch * 256, WIHs + (size_t)l * NC * 192 * 256,
                gB + l * 768, IG, mch, 768, 256, 0);
            k_scanp<<<dim3(NC, bch), dim3(64), 0, stream>>>(
                IG, gWhh + (size_t)l * NC * 192 * 64, gBn + l * NC * 64, logS + l * NC,
                h0 + (size_t)l * NC * NB * 64,
                ynew_f + (size_t)l * NC * NB * NT * 64, XC, ch * bch);
        }
        // inter-layer MLP (XB aliases IG; IG dead after scans consumed it)
        k_gemm_f32<<<dim3(MR / 64, 256 / 64), blk, 0, stream>>>(
            XC, mW1 + (size_t)l * 256 * 256, mB1 + l * 256, XB, MR, 256, 256, 1);
        k_gemm_f32<<<dim3(MR / 64, 256 / 64), blk, 0, stream>>>(
            XB, mW2 + (size_t)l * 256 * 256, mB2 + l * 256, XA, MR, 256, 256, 0);
    }
    // faithful to source: mlps[-1] applied a second time -> out (f32)
    k_gemm_f32<<<dim3(MR / 64, 256 / 64), blk, 0, stream>>>(
        XA, mW1 + (size_t)2 * 256 * 256, mB1 + 2 * 256, XB, MR, 256, 256, 1);
    k_gemm_f32<<<dim3(MR / 64, 256 / 64), blk, 0, stream>>>(
        XB, mW2 + (size_t)2 * 256 * 256, mB2 + 2 * 256, out_f, MR, 256, 256, 0);
}